// Round 17
// baseline (358.569 us; speedup 1.0000x reference)
//
#include <hip/hip_runtime.h>
#include <math.h>

#define N_ROWS 8192
#define DIMS   1024
#define NCLS   512
#define BK     32
#define NT     (DIMS / BK)           // 32 K-tiles
#define NQ     64                    // 8192/128 col-blocks
#define NWG2   1056                  // triangular 256x128 tiles (= 8*132)
#define SLABSH (512 * BK)            // shorts per slab: Ah256 + Bh128 + Bl128 rows
#define CA     16                    // class rows staged per LDS chunk (64 KB)

typedef __attribute__((ext_vector_type(8))) short bf16x8;
typedef __attribute__((ext_vector_type(4))) float f32x4;
typedef unsigned long long ull;

// ---------- helpers ----------
__device__ __forceinline__ unsigned short f2bf(float f) {
    unsigned u = __float_as_uint(f);
    u += 0x7FFFu + ((u >> 16) & 1u);   // RNE
    return (unsigned short)(u >> 16);
}
__device__ __forceinline__ float bf2f(unsigned short h) {
    return __uint_as_float(((unsigned)h) << 16);
}
// monotone float<->uint for atomic min/max
__device__ __forceinline__ unsigned enc_f(float x) {
    unsigned u = __float_as_uint(x);
    return (u & 0x80000000u) ? ~u : (u | 0x80000000u);
}
__device__ __forceinline__ float dec_f(unsigned u) {
    return (u & 0x80000000u) ? __uint_as_float(u ^ 0x80000000u) : __uint_as_float(~u);
}

__device__ __forceinline__ float dot1024(const float* __restrict__ xi,
                                         const float* __restrict__ xj) {
    const float4* u4 = (const float4*)xi;
    const float4* v4 = (const float4*)xj;
    float a0 = 0.f, a1 = 0.f, a2 = 0.f, a3 = 0.f;
#pragma unroll 8
    for (int q = 0; q < DIMS / 4; ++q) {
        float4 u = u4[q], v = v4[q];
        a0 += u.x * v.x; a1 += u.y * v.y;
        a2 += u.z * v.z; a3 += u.w * v.w;
    }
    return (a0 + a1) + (a2 + a3);
}

typedef __attribute__((address_space(1))) const void* as1_cvp;
typedef __attribute__((address_space(3))) void* as3_vp;
__device__ __forceinline__ void gl_lds16(const void* g, void* l) {
    __builtin_amdgcn_global_load_lds((as1_cvp)g, (as3_vp)l, 16, 0, 0);
}

// ---------- fused setup: block 0 = bucketing, blocks 1..2048 = prep + init ----------
__global__ __launch_bounds__(256) void setup_k(const float* __restrict__ X,
                                               const int* __restrict__ raw,
                                               short* __restrict__ Xhi,
                                               short* __restrict__ Xlo,
                                               float* __restrict__ sumsq,
                                               int* __restrict__ tgt,
                                               int* __restrict__ cnt,
                                               int* __restrict__ offs,
                                               int* __restrict__ pairoff,
                                               int* __restrict__ members,
                                               int* __restrict__ an_cnt,
                                               float* __restrict__ neg_sum,
                                               ull* __restrict__ maxneg,
                                               float* __restrict__ out,
                                               int simcap) {
    __shared__ int sflag;
    __shared__ int scnt[NCLS], soff[NCLS], spair[NCLS], scur[NCLS];
    __shared__ int schunk[16], schunkp[16];
    int tid = threadIdx.x;

    if (blockIdx.x == 0) {
        if (tid == 0) { sflag = 0; out[0] = 0.f; out[1 + 3 * N_ROWS] = 0.f; }
        for (int c = tid; c < NCLS; c += 256) scnt[c] = 0;
        __syncthreads();
        int any = 0;
        for (int i = tid; i < N_ROWS / 2; i += 256) any |= raw[2 * i + 1];
        if (any) atomicOr(&sflag, 1);
        __syncthreads();
        int is32 = sflag;     // nonzero odd 32-bit words => targets are int32
        for (int i = tid; i < N_ROWS; i += 256) {
            int t = is32 ? raw[i] : raw[2 * i];
            tgt[i] = t;
            if ((unsigned)t < NCLS) atomicAdd(&scnt[t], 1);
        }
        __syncthreads();
        if (tid < 16) {
            int s = 0, sp = 0;
            for (int c = tid * 32; c < tid * 32 + 32; ++c) {
                int k = scnt[c]; int kk = k < 256 ? k : 256;
                s += k; sp += kk * kk;
            }
            schunk[tid] = s; schunkp[tid] = sp;
        }
        __syncthreads();
        if (tid == 0) {
            int s = 0, sp = 0;
            for (int t = 0; t < 16; ++t) {
                int a = schunk[t], b = schunkp[t];
                schunk[t] = s; schunkp[t] = sp;
                s += a; sp += b;
            }
        }
        __syncthreads();
        if (tid < 16) {
            int s = schunk[tid], sp = schunkp[tid];
            for (int c = tid * 32; c < tid * 32 + 32; ++c) {
                int k = scnt[c]; int kk = k < 256 ? k : 256;
                soff[c] = s; scur[c] = s;
                spair[c] = (simcap > 0 && sp + kk * kk <= simcap) ? sp : -1;
                s += k; sp += kk * kk;
            }
        }
        __syncthreads();
        for (int i = tid; i < N_ROWS; i += 256) {
            int t = tgt[i];
            if ((unsigned)t < NCLS) {
                int p = atomicAdd(&scur[t], 1);
                members[p] = i;
            }
        }
        for (int c = tid; c < NCLS; c += 256) {
            cnt[c] = scnt[c]; offs[c] = soff[c]; pairoff[c] = spair[c];
        }
    } else {
        int rowbase = (blockIdx.x - 1) * 4;
        int row  = rowbase + (tid >> 6);
        int lane = tid & 63;
        const float4* xr = (const float4*)(X + (size_t)row * DIMS);
        short4* oh = (short4*)(Xhi + (size_t)row * DIMS);
        short4* ol = (short4*)(Xlo + (size_t)row * DIMS);
        float ss = 0.f;
#pragma unroll
        for (int t = 0; t < 4; ++t) {
            float4 v = xr[lane + 64 * t];
            ss += v.x * v.x + v.y * v.y + v.z * v.z + v.w * v.w;
            short4 h, l;
            unsigned short hx = f2bf(v.x); h.x = (short)hx; l.x = (short)f2bf(v.x - bf2f(hx));
            unsigned short hy = f2bf(v.y); h.y = (short)hy; l.y = (short)f2bf(v.y - bf2f(hy));
            unsigned short hz = f2bf(v.z); h.z = (short)hz; l.z = (short)f2bf(v.z - bf2f(hz));
            unsigned short hw = f2bf(v.w); h.w = (short)hw; l.w = (short)f2bf(v.w - bf2f(hw));
            oh[lane + 64 * t] = h;
            ol[lane + 64 * t] = l;
        }
#pragma unroll
        for (int off = 1; off < 64; off <<= 1) ss += __shfl_xor(ss, off);
        if (lane == 0) sumsq[row] = ss;
        if (tid < 4) {
            int r = rowbase + tid;
            an_cnt[r] = 0; neg_sum[r] = 0.f;
            maxneg[r] = ((ull)enc_f(-1e9f)) << 32;
        }
    }
}

// ---------- min_pos: LDS-staged class grams, 8 waves, a-loop unrolled x2 ----------
__global__ __launch_bounds__(512) void minpos_k(const float* __restrict__ X,
                                                const int* __restrict__ members,
                                                const int* __restrict__ offs,
                                                const int* __restrict__ cnt,
                                                const int* __restrict__ pairoff,
                                                const float* __restrict__ sumsq,
                                                float* __restrict__ minpos,
                                                float* __restrict__ simbuf) {
    __shared__ __align__(16) float srows[CA][DIMS];   // 64 KB
    __shared__ unsigned smin[256];
    int c = blockIdx.x, tid = threadIdx.x;
    int wave = tid >> 6, lane = tid & 63;             // 8 waves
    int k = cnt[c], off = offs[c], spo = pairoff[c];
    for (int t = tid; t < 256; t += 512) smin[t] = enc_f(1e9f);
    int kk = k < 256 ? k : 256;
    __syncthreads();
    for (int a0 = 0; a0 < kk; a0 += CA) {
        int na = (kk - a0 < CA) ? (kk - a0) : CA;
        for (int idx = tid; idx < na * 256; idx += 512) {
            int r = idx >> 8, c4 = idx & 255;
            int i = members[off + a0 + r];
            ((float4*)&srows[r][0])[c4] = ((const float4*)(X + (size_t)i * DIMS))[c4];
        }
        __syncthreads();
        for (int b = wave; b < kk; b += 8) {
            int j = members[off + b];
            const float4* xj = (const float4*)(X + (size_t)j * DIMS);
            float4 rj[4];
#pragma unroll
            for (int t = 0; t < 4; ++t) rj[t] = xj[lane + 64 * t];
            int a = 0;
            for (; a + 2 <= na; a += 2) {
                int i0 = members[off + a0 + a];
                int i1 = members[off + a0 + a + 1];
                float p0 = 0.f, p1 = 0.f, p2 = 0.f, p3 = 0.f;
                float q0 = 0.f, q1 = 0.f, q2 = 0.f, q3 = 0.f;
#pragma unroll
                for (int t = 0; t < 4; ++t) {
                    float4 u0 = ((const float4*)&srows[a][0])[lane + 64 * t];
                    float4 u1 = ((const float4*)&srows[a + 1][0])[lane + 64 * t];
                    p0 += u0.x * rj[t].x; p1 += u0.y * rj[t].y;
                    p2 += u0.z * rj[t].z; p3 += u0.w * rj[t].w;
                    q0 += u1.x * rj[t].x; q1 += u1.y * rj[t].y;
                    q2 += u1.z * rj[t].z; q3 += u1.w * rj[t].w;
                }
                float s0 = (p0 + p1) + (p2 + p3);
                float s1 = (q0 + q1) + (q2 + q3);
#pragma unroll
                for (int o = 1; o < 64; o <<= 1) {
                    s0 += __shfl_xor(s0, o);
                    s1 += __shfl_xor(s1, o);
                }
                if (i0 == j) s0 = sumsq[i0];
                if (i1 == j) s1 = sumsq[i1];
                if (lane == 0) {
                    if (spo >= 0) {
                        simbuf[spo + (a0 + a) * kk + b] = s0;
                        simbuf[spo + (a0 + a + 1) * kk + b] = s1;
                    }
                    if (s0 < 1.0f) atomicMin(&smin[a0 + a], enc_f(s0));
                    if (s1 < 1.0f) atomicMin(&smin[a0 + a + 1], enc_f(s1));
                }
            }
            if (a < na) {
                int i0 = members[off + a0 + a];
                float p0 = 0.f, p1 = 0.f, p2 = 0.f, p3 = 0.f;
#pragma unroll
                for (int t = 0; t < 4; ++t) {
                    float4 u0 = ((const float4*)&srows[a][0])[lane + 64 * t];
                    p0 += u0.x * rj[t].x; p1 += u0.y * rj[t].y;
                    p2 += u0.z * rj[t].z; p3 += u0.w * rj[t].w;
                }
                float s0 = (p0 + p1) + (p2 + p3);
#pragma unroll
                for (int o = 1; o < 64; o <<= 1) s0 += __shfl_xor(s0, o);
                if (i0 == j) s0 = sumsq[i0];
                if (lane == 0) {
                    if (spo >= 0) simbuf[spo + (a0 + a) * kk + b] = s0;
                    if (s0 < 1.0f) atomicMin(&smin[a0 + a], enc_f(s0));
                }
            }
        }
        __syncthreads();
    }
    for (int a = tid; a < kk; a += 512) minpos[members[off + a]] = dec_f(smin[a]);
}

// ---------- main fused GEMM: 256x128, BK=32, 3-slab depth-2 counted-vmcnt ----------
__global__ __launch_bounds__(512, 1) void fused_k(const short* __restrict__ Xhi,
                                                  const short* __restrict__ Xlo,
                                                  const int* __restrict__ tgt,
                                                  const float* __restrict__ margin,
                                                  const float* __restrict__ minpos,
                                                  ull* __restrict__ maxneg,
                                                  int* __restrict__ an_cnt,
                                                  float* __restrict__ neg_sum) {
    // slab layout (shorts): Ah rows 0..255 at 0, Bh rows at 256*BK, Bl at 384*BK
    __shared__ __align__(16) short lds[3 * SLABSH];   // 96 KB

    // bijective XCD-aware swizzle (1056 = 8*132)
    int orig = blockIdx.x;
    int wgid = (orig & 7) * (NWG2 / 8) + (orig >> 3);

    // triangular decode: 256-row block p, 128-col block q, q >= 2p
    int rem = wgid, p = 0;
    while (rem >= NQ - 2 * p) { rem -= NQ - 2 * p; ++p; }
    int q = 2 * p + rem;
    int row0 = p * 256, col0 = q * 128;

    int tid = threadIdx.x, lane = tid & 63, wave = tid >> 6;
    int wr = wave >> 1, wc = wave & 1;          // 4M x 2N; per-wave 64x64 out
    int l15 = lane & 15, l4 = lane >> 4;

    // staging: 32 chunks of 16 rows x 32 cols (1 KB); wave w takes u = w + 8j
    const short* gp[4];
    int lof[4];
#pragma unroll
    for (int j = 0; j < 4; ++j) {
        int u = wave + 8 * j;               // 0..31
        const short* src; int base0, r16, sbase;
        if (u < 16)      { src = Xhi; base0 = row0; r16 = u * 16;        sbase = 0; }
        else if (u < 24) { src = Xhi; base0 = col0; r16 = (u - 16) * 16; sbase = 256 * BK; }
        else             { src = Xlo; base0 = col0; r16 = (u - 24) * 16; sbase = 384 * BK; }
        gp[j] = src + (size_t)(base0 + r16 + (lane >> 2)) * DIMS + (lane & 3) * 8;
        lof[j] = sbase + r16 * BK;
    }

    f32x4 acc[4][4] = {};

    // prologue: stage K-tiles 0,1,2 into slabs 0,1,2 (12 loads in flight)
#pragma unroll
    for (int tt = 0; tt < 3; ++tt) {
        short* S = lds + tt * SLABSH;
#pragma unroll
        for (int j = 0; j < 4; ++j) gl_lds16(gp[j] + (size_t)tt * BK, S + lof[j]);
    }

    int cur = 0;
#pragma unroll 1
    for (int t = 0; t < NT; ++t) {
        // gate: own stage(t) loads complete (stages t+1, t+2 may stay in flight)
        if (t < NT - 2)      asm volatile("s_waitcnt vmcnt(8)" ::: "memory");
        else if (t == NT - 2) asm volatile("s_waitcnt vmcnt(4)" ::: "memory");
        else                  asm volatile("s_waitcnt vmcnt(0)" ::: "memory");
        __builtin_amdgcn_s_barrier();     // all waves gated -> slab[cur] globally ready

        short* S = lds + cur * SLABSH;
        bf16x8 bh[4], bl[4];
#pragma unroll
        for (int n = 0; n < 4; ++n) {
            int rb = wc * 64 + n * 16 + l15;
            bh[n] = *(const bf16x8*)(S + (256 + rb) * BK + l4 * 8);
            bl[n] = *(const bf16x8*)(S + (384 + rb) * BK + l4 * 8);
        }
        __builtin_amdgcn_s_setprio(1);
#pragma unroll
        for (int m = 0; m < 4; ++m) {
            int ra = wr * 64 + m * 16 + l15;
            bf16x8 ah = *(const bf16x8*)(S + ra * BK + l4 * 8);
#pragma unroll
            for (int n = 0; n < 4; ++n) {
                acc[m][n] = __builtin_amdgcn_mfma_f32_16x16x32_bf16(ah, bh[n], acc[m][n], 0, 0, 0);
                acc[m][n] = __builtin_amdgcn_mfma_f32_16x16x32_bf16(ah, bl[n], acc[m][n], 0, 0, 0);
            }
        }
        __builtin_amdgcn_s_setprio(0);
        __syncthreads();                  // all waves done reading slab[cur]
        if (t + 3 < NT) {
#pragma unroll
            for (int j = 0; j < 4; ++j)
                gl_lds16(gp[j] + (size_t)(t + 3) * BK, S + lof[j]);
        }
        cur = (cur == 2) ? 0 : cur + 1;
    }

    // ---- epilogue: per-cell predicate gc > grow; both endpoints updated once ----
    int tcol[4]; float mcol[4], pcol[4];
#pragma unroll
    for (int n = 0; n < 4; ++n) {
        int gc = col0 + wc * 64 + n * 16 + l15;
        tcol[n] = tgt[gc];
        mcol[n] = margin[gc];
        pcol[n] = minpos[gc];
    }
    ull  cmx[4] = {0, 0, 0, 0};
    float cns[4] = {0, 0, 0, 0};
    int  cct[4] = {0, 0, 0, 0};

#pragma unroll
    for (int m = 0; m < 4; ++m) {
#pragma unroll
        for (int r = 0; r < 4; ++r) {
            int grow = row0 + wr * 64 + m * 16 + l4 * 4 + r;
            int trow = tgt[grow];
            float mg = margin[grow], mp = minpos[grow];
            ull rmx = 0; float rns = 0.f; int rct = 0;
#pragma unroll
            for (int n = 0; n < 4; ++n) {
                float s = acc[m][n][r];
                int gc = col0 + wc * 64 + n * 16 + l15;
                if (trow != tcol[n] && gc > grow) {
                    float e = __expf(10.f * s - 5.f);
                    ull pk = (((ull)enc_f(s)) << 32) | (unsigned)gc;
                    rmx = rmx > pk ? rmx : pk;
                    if (s + mg - mp > 0.f) { rct++; rns += e; }
                    ull pk2 = (((ull)enc_f(s)) << 32) | (unsigned)grow;
                    cmx[n] = cmx[n] > pk2 ? cmx[n] : pk2;
                    if (s + mcol[n] - pcol[n] > 0.f) { cct[n]++; cns[n] += e; }
                }
            }
#pragma unroll
            for (int off = 1; off < 16; off <<= 1) {
                ull o = __shfl_xor(rmx, off); rmx = rmx > o ? rmx : o;
                rns += __shfl_xor(rns, off);
                rct += __shfl_xor(rct, off);
            }
            if (l15 == 0 && rmx != 0) {
                atomicMax(&maxneg[grow], rmx);
                if (rct) { atomicAdd(&an_cnt[grow], rct); atomicAdd(&neg_sum[grow], rns); }
            }
        }
    }
#pragma unroll
    for (int n = 0; n < 4; ++n) {
#pragma unroll
        for (int off = 16; off < 64; off <<= 1) {
            ull o = __shfl_xor(cmx[n], off); cmx[n] = cmx[n] > o ? cmx[n] : o;
            cns[n] += __shfl_xor(cns[n], off);
            cct[n] += __shfl_xor(cct[n], off);
        }
        if (lane < 16 && cmx[n] != 0) {
            int gc = col0 + wc * 64 + n * 16 + l15;
            atomicMax(&maxneg[gc], cmx[n]);
            if (cct[n]) { atomicAdd(&an_cnt[gc], cct[n]); atomicAdd(&neg_sum[gc], cns[n]); }
        }
    }
}

// ---------- positive path + argmax repair + outputs + scalar reduction ----------
__global__ __launch_bounds__(256) void finalize_k(const float* __restrict__ X,
                                                  const int* __restrict__ members,
                                                  const int* __restrict__ offs,
                                                  const int* __restrict__ cnt,
                                                  const int* __restrict__ pairoff,
                                                  const float* __restrict__ simbuf,
                                                  const float* __restrict__ sumsq,
                                                  const float* __restrict__ margin,
                                                  const ull* __restrict__ maxneg,
                                                  const int* __restrict__ an_cnt,
                                                  const float* __restrict__ neg_sum,
                                                  float* __restrict__ out) {
    __shared__ int sap[256];
    __shared__ float sps[256];
    __shared__ float smn[256], smg[256];
    __shared__ float sred[8];
    int c = blockIdx.x, tid = threadIdx.x;
    int wave = tid >> 6, lane = tid & 63;
    int k = cnt[c], off = offs[c], spo = pairoff[c];
    int kk = k < 256 ? k : 256;
    sap[tid] = 0; sps[tid] = 0.f;

    for (int a = wave; a < kk; a += 4) {
        int i = members[off + a];
        ull pm = maxneg[i];
        float mn = -1e9f;
        if ((unsigned)(pm >> 32) != enc_f(-1e9f)) {
            int col = (int)(pm & 0xFFFFFFFFu);
            const float4* xi = (const float4*)(X + (size_t)i * DIMS);
            const float4* xj = (const float4*)(X + (size_t)col * DIMS);
            float a0 = 0.f, a1 = 0.f, a2 = 0.f, a3 = 0.f;
#pragma unroll
            for (int t = 0; t < 4; ++t) {
                float4 u = xi[lane + 64 * t], v = xj[lane + 64 * t];
                a0 += u.x * v.x; a1 += u.y * v.y;
                a2 += u.z * v.z; a3 += u.w * v.w;
            }
            float s = (a0 + a1) + (a2 + a3);
#pragma unroll
            for (int o = 1; o < 64; o <<= 1) s += __shfl_xor(s, o);
            mn = s;
        }
        if (lane == 0) { smn[a] = mn; smg[a] = margin[i]; }
    }
    __syncthreads();

    for (int p = tid; p < kk * kk; p += 256) {
        int a = p / kk;
        float s;
        if (spo >= 0) {
            s = simbuf[spo + p];
        } else {
            int b = p - a * kk;
            int i = members[off + a], j = members[off + b];
            s = (i == j) ? sumsq[i]
                         : dot1024(X + (size_t)i * DIMS, X + (size_t)j * DIMS);
        }
        if (s < 1.0f && (smn[a] - s + smg[a] > 0.f)) {
            atomicAdd(&sap[a], 1);
            atomicAdd(&sps[a], __expf(-2.f * s + 1.f));
        }
    }
    __syncthreads();

    float bl = 0.f, bt = 0.f;
    for (int a = tid; a < kk; a += 256) {
        int i = members[off + a];
        int ap = sap[a];
        int an = an_cnt[i];
        bool valid = (ap > 0) && (an > 0);
        float pl = log1pf(sps[a]);
        float nl = 0.2f * log1pf(neg_sum[i]);
        out[1 + i]              = valid ? 1.f : 0.f;
        out[1 + N_ROWS + i]     = valid ? (float)ap : 0.f;
        out[1 + 2 * N_ROWS + i] = valid ? (float)an : 0.f;
        bl += valid ? (pl + nl) : 0.f;
        bt += valid ? (float)(ap + an) : 0.f;
    }
#pragma unroll
    for (int o = 1; o < 64; o <<= 1) {
        bl += __shfl_xor(bl, o);
        bt += __shfl_xor(bt, o);
    }
    if (lane == 0) { sred[wave] = bl; sred[4 + wave] = bt; }
    __syncthreads();
    if (tid == 0) {
        float L = sred[0] + sred[1] + sred[2] + sred[3];
        float T = sred[4] + sred[5] + sred[6] + sred[7];
        atomicAdd(&out[0], L / (float)N_ROWS);
        atomicAdd(&out[1 + 3 * N_ROWS], T);
    }
}

// ---------- host ----------
extern "C" void kernel_launch(void* const* d_in, const int* in_sizes, int n_in,
                              void* d_out, int out_size, void* d_ws, size_t ws_size,
                              hipStream_t stream) {
    const float* X      = (const float*)d_in[0];
    const int*   rawTgt = (const int*)d_in[1];
    const float* margin = (const float*)d_in[2];
    float* out = (float*)d_out;

    char* ws = (char*)d_ws;
    short* Xhi = (short*)ws;                                   // 16 MB
    short* Xlo = (short*)(ws + (size_t)16 * 1024 * 1024);      // 16 MB
    char* p = ws + (size_t)32 * 1024 * 1024;
    float* sumsq    = (float*)p;  p += (size_t)N_ROWS * 4;
    float* minpos   = (float*)p;  p += (size_t)N_ROWS * 4;
    ull*   maxneg   = (ull*)p;    p += (size_t)N_ROWS * 8;
    int*   an_cnt   = (int*)p;    p += (size_t)N_ROWS * 4;
    float* neg_sum  = (float*)p;  p += (size_t)N_ROWS * 4;
    int*   tgt      = (int*)p;    p += (size_t)N_ROWS * 4;
    int*   members  = (int*)p;    p += (size_t)N_ROWS * 4;
    int*   cnt      = (int*)p;    p += (size_t)NCLS * 4;
    int*   offs     = (int*)p;    p += (size_t)NCLS * 4;
    int*   pairoff  = (int*)p;    p += (size_t)NCLS * 4;
    float* simbuf   = (float*)p;  // up to 4 MB if workspace allows

    size_t used = (size_t)(p - ws);
    int simcap = (ws_size >= used + (size_t)4 * 1024 * 1024) ? (1 << 20) : 0;

    setup_k<<<1 + N_ROWS / 4, 256, 0, stream>>>(X, rawTgt, Xhi, Xlo, sumsq, tgt, cnt, offs,
                                                pairoff, members, an_cnt, neg_sum, maxneg,
                                                out, simcap);
    minpos_k<<<NCLS, 512, 0, stream>>>(X, members, offs, cnt, pairoff, sumsq, minpos, simbuf);
    fused_k<<<NWG2, 512, 0, stream>>>(Xhi, Xlo, tgt, margin, minpos, maxneg, an_cnt, neg_sum);
    finalize_k<<<NCLS, 256, 0, stream>>>(X, members, offs, cnt, pairoff, simbuf, sumsq,
                                         margin, maxneg, an_cnt, neg_sum, out);
}

// Round 18
// 296.816 us; speedup vs baseline: 1.2080x; 1.2080x over previous
//
#include <hip/hip_runtime.h>
#include <math.h>

#define N_ROWS 8192
#define DIMS   1024
#define NCLS   512
#define BK     32
#define NT     (DIMS / BK)           // 32 K-tiles
#define NQ     64                    // 8192/128 col-blocks
#define NWG2   1056                  // triangular 256x128 tiles (= 8*132)
#define SLABSH (512 * BK)            // shorts per slab: Ah256 + Bh128 + Bl128 rows
#define CA     16                    // class rows staged per LDS chunk (64 KB)

typedef __attribute__((ext_vector_type(8))) short bf16x8;
typedef __attribute__((ext_vector_type(4))) float f32x4;
typedef unsigned long long ull;

// ---------- helpers ----------
__device__ __forceinline__ unsigned short f2bf(float f) {
    unsigned u = __float_as_uint(f);
    u += 0x7FFFu + ((u >> 16) & 1u);   // RNE
    return (unsigned short)(u >> 16);
}
__device__ __forceinline__ float bf2f(unsigned short h) {
    return __uint_as_float(((unsigned)h) << 16);
}
// monotone float<->uint for atomic min/max
__device__ __forceinline__ unsigned enc_f(float x) {
    unsigned u = __float_as_uint(x);
    return (u & 0x80000000u) ? ~u : (u | 0x80000000u);
}
__device__ __forceinline__ float dec_f(unsigned u) {
    return (u & 0x80000000u) ? __uint_as_float(u ^ 0x80000000u) : __uint_as_float(~u);
}

__device__ __forceinline__ float dot1024(const float* __restrict__ xi,
                                         const float* __restrict__ xj) {
    const float4* u4 = (const float4*)xi;
    const float4* v4 = (const float4*)xj;
    float a0 = 0.f, a1 = 0.f, a2 = 0.f, a3 = 0.f;
#pragma unroll 8
    for (int q = 0; q < DIMS / 4; ++q) {
        float4 u = u4[q], v = v4[q];
        a0 += u.x * v.x; a1 += u.y * v.y;
        a2 += u.z * v.z; a3 += u.w * v.w;
    }
    return (a0 + a1) + (a2 + a3);
}

typedef __attribute__((address_space(1))) const void* as1_cvp;
typedef __attribute__((address_space(3))) void* as3_vp;
__device__ __forceinline__ void gl_lds16(const void* g, void* l) {
    __builtin_amdgcn_global_load_lds((as1_cvp)g, (as3_vp)l, 16, 0, 0);
}

// ---------- fused setup: block 0 = bucketing, blocks 1..2048 = prep + init ----------
__global__ __launch_bounds__(256) void setup_k(const float* __restrict__ X,
                                               const int* __restrict__ raw,
                                               short* __restrict__ Xhi,
                                               short* __restrict__ Xlo,
                                               float* __restrict__ sumsq,
                                               int* __restrict__ tgt,
                                               int* __restrict__ cnt,
                                               int* __restrict__ offs,
                                               int* __restrict__ pairoff,
                                               int* __restrict__ members,
                                               int* __restrict__ an_cnt,
                                               float* __restrict__ neg_sum,
                                               ull* __restrict__ maxneg,
                                               float* __restrict__ out,
                                               int simcap) {
    __shared__ int sflag;
    __shared__ int scnt[NCLS], soff[NCLS], spair[NCLS], scur[NCLS];
    __shared__ int schunk[16], schunkp[16];
    int tid = threadIdx.x;

    if (blockIdx.x == 0) {
        if (tid == 0) { sflag = 0; out[0] = 0.f; out[1 + 3 * N_ROWS] = 0.f; }
        for (int c = tid; c < NCLS; c += 256) scnt[c] = 0;
        __syncthreads();
        int any = 0;
        for (int i = tid; i < N_ROWS / 2; i += 256) any |= raw[2 * i + 1];
        if (any) atomicOr(&sflag, 1);
        __syncthreads();
        int is32 = sflag;     // nonzero odd 32-bit words => targets are int32
        for (int i = tid; i < N_ROWS; i += 256) {
            int t = is32 ? raw[i] : raw[2 * i];
            tgt[i] = t;
            if ((unsigned)t < NCLS) atomicAdd(&scnt[t], 1);
        }
        __syncthreads();
        if (tid < 16) {
            int s = 0, sp = 0;
            for (int c = tid * 32; c < tid * 32 + 32; ++c) {
                int k = scnt[c]; int kk = k < 256 ? k : 256;
                s += k; sp += kk * kk;
            }
            schunk[tid] = s; schunkp[tid] = sp;
        }
        __syncthreads();
        if (tid == 0) {
            int s = 0, sp = 0;
            for (int t = 0; t < 16; ++t) {
                int a = schunk[t], b = schunkp[t];
                schunk[t] = s; schunkp[t] = sp;
                s += a; sp += b;
            }
        }
        __syncthreads();
        if (tid < 16) {
            int s = schunk[tid], sp = schunkp[tid];
            for (int c = tid * 32; c < tid * 32 + 32; ++c) {
                int k = scnt[c]; int kk = k < 256 ? k : 256;
                soff[c] = s; scur[c] = s;
                spair[c] = (simcap > 0 && sp + kk * kk <= simcap) ? sp : -1;
                s += k; sp += kk * kk;
            }
        }
        __syncthreads();
        for (int i = tid; i < N_ROWS; i += 256) {
            int t = tgt[i];
            if ((unsigned)t < NCLS) {
                int p = atomicAdd(&scur[t], 1);
                members[p] = i;
            }
        }
        for (int c = tid; c < NCLS; c += 256) {
            cnt[c] = scnt[c]; offs[c] = soff[c]; pairoff[c] = spair[c];
        }
    } else {
        int rowbase = (blockIdx.x - 1) * 4;
        int row  = rowbase + (tid >> 6);
        int lane = tid & 63;
        const float4* xr = (const float4*)(X + (size_t)row * DIMS);
        short4* oh = (short4*)(Xhi + (size_t)row * DIMS);
        short4* ol = (short4*)(Xlo + (size_t)row * DIMS);
        float ss = 0.f;
#pragma unroll
        for (int t = 0; t < 4; ++t) {
            float4 v = xr[lane + 64 * t];
            ss += v.x * v.x + v.y * v.y + v.z * v.z + v.w * v.w;
            short4 h, l;
            unsigned short hx = f2bf(v.x); h.x = (short)hx; l.x = (short)f2bf(v.x - bf2f(hx));
            unsigned short hy = f2bf(v.y); h.y = (short)hy; l.y = (short)f2bf(v.y - bf2f(hy));
            unsigned short hz = f2bf(v.z); h.z = (short)hz; l.z = (short)f2bf(v.z - bf2f(hz));
            unsigned short hw = f2bf(v.w); h.w = (short)hw; l.w = (short)f2bf(v.w - bf2f(hw));
            oh[lane + 64 * t] = h;
            ol[lane + 64 * t] = l;
        }
#pragma unroll
        for (int off = 1; off < 64; off <<= 1) ss += __shfl_xor(ss, off);
        if (lane == 0) sumsq[row] = ss;
        if (tid < 4) {
            int r = rowbase + tid;
            an_cnt[r] = 0; neg_sum[r] = 0.f;
            maxneg[r] = ((ull)enc_f(-1e9f)) << 32;
        }
    }
}

// ---------- min_pos: LDS-staged class grams, 8 waves, a-loop unrolled x2 ----------
__global__ __launch_bounds__(512) void minpos_k(const float* __restrict__ X,
                                                const int* __restrict__ members,
                                                const int* __restrict__ offs,
                                                const int* __restrict__ cnt,
                                                const int* __restrict__ pairoff,
                                                const float* __restrict__ sumsq,
                                                float* __restrict__ minpos,
                                                float* __restrict__ simbuf) {
    __shared__ __align__(16) float srows[CA][DIMS];   // 64 KB
    __shared__ unsigned smin[256];
    int c = blockIdx.x, tid = threadIdx.x;
    int wave = tid >> 6, lane = tid & 63;             // 8 waves
    int k = cnt[c], off = offs[c], spo = pairoff[c];
    for (int t = tid; t < 256; t += 512) smin[t] = enc_f(1e9f);
    int kk = k < 256 ? k : 256;
    __syncthreads();
    for (int a0 = 0; a0 < kk; a0 += CA) {
        int na = (kk - a0 < CA) ? (kk - a0) : CA;
        for (int idx = tid; idx < na * 256; idx += 512) {
            int r = idx >> 8, c4 = idx & 255;
            int i = members[off + a0 + r];
            ((float4*)&srows[r][0])[c4] = ((const float4*)(X + (size_t)i * DIMS))[c4];
        }
        __syncthreads();
        for (int b = wave; b < kk; b += 8) {
            int j = members[off + b];
            const float4* xj = (const float4*)(X + (size_t)j * DIMS);
            float4 rj[4];
#pragma unroll
            for (int t = 0; t < 4; ++t) rj[t] = xj[lane + 64 * t];
            int a = 0;
            for (; a + 2 <= na; a += 2) {
                int i0 = members[off + a0 + a];
                int i1 = members[off + a0 + a + 1];
                float p0 = 0.f, p1 = 0.f, p2 = 0.f, p3 = 0.f;
                float q0 = 0.f, q1 = 0.f, q2 = 0.f, q3 = 0.f;
#pragma unroll
                for (int t = 0; t < 4; ++t) {
                    float4 u0 = ((const float4*)&srows[a][0])[lane + 64 * t];
                    float4 u1 = ((const float4*)&srows[a + 1][0])[lane + 64 * t];
                    p0 += u0.x * rj[t].x; p1 += u0.y * rj[t].y;
                    p2 += u0.z * rj[t].z; p3 += u0.w * rj[t].w;
                    q0 += u1.x * rj[t].x; q1 += u1.y * rj[t].y;
                    q2 += u1.z * rj[t].z; q3 += u1.w * rj[t].w;
                }
                float s0 = (p0 + p1) + (p2 + p3);
                float s1 = (q0 + q1) + (q2 + q3);
#pragma unroll
                for (int o = 1; o < 64; o <<= 1) {
                    s0 += __shfl_xor(s0, o);
                    s1 += __shfl_xor(s1, o);
                }
                if (i0 == j) s0 = sumsq[i0];
                if (i1 == j) s1 = sumsq[i1];
                if (lane == 0) {
                    if (spo >= 0) {
                        simbuf[spo + (a0 + a) * kk + b] = s0;
                        simbuf[spo + (a0 + a + 1) * kk + b] = s1;
                    }
                    if (s0 < 1.0f) atomicMin(&smin[a0 + a], enc_f(s0));
                    if (s1 < 1.0f) atomicMin(&smin[a0 + a + 1], enc_f(s1));
                }
            }
            if (a < na) {
                int i0 = members[off + a0 + a];
                float p0 = 0.f, p1 = 0.f, p2 = 0.f, p3 = 0.f;
#pragma unroll
                for (int t = 0; t < 4; ++t) {
                    float4 u0 = ((const float4*)&srows[a][0])[lane + 64 * t];
                    p0 += u0.x * rj[t].x; p1 += u0.y * rj[t].y;
                    p2 += u0.z * rj[t].z; p3 += u0.w * rj[t].w;
                }
                float s0 = (p0 + p1) + (p2 + p3);
#pragma unroll
                for (int o = 1; o < 64; o <<= 1) s0 += __shfl_xor(s0, o);
                if (i0 == j) s0 = sumsq[i0];
                if (lane == 0) {
                    if (spo >= 0) simbuf[spo + (a0 + a) * kk + b] = s0;
                    if (s0 < 1.0f) atomicMin(&smin[a0 + a], enc_f(s0));
                }
            }
        }
        __syncthreads();
    }
    for (int a = tid; a < kk; a += 512) minpos[members[off + a]] = dec_f(smin[a]);
}

// ---------- main fused GEMM: 256x128, BK=32, stage-first dbuf + 2-bit T2 swizzle ----------
// LDS[row][cu] (cu = 16B col unit 0..3) holds global col unit (cu ^ (row&3));
// same involution on write (pre-swizzled global source) and read. [rule #21]
__global__ __launch_bounds__(512, 4) void fused_k(const short* __restrict__ Xhi,
                                                  const short* __restrict__ Xlo,
                                                  const int* __restrict__ tgt,
                                                  const float* __restrict__ margin,
                                                  const float* __restrict__ minpos,
                                                  ull* __restrict__ maxneg,
                                                  int* __restrict__ an_cnt,
                                                  float* __restrict__ neg_sum) {
    // slab layout (shorts): Ah rows 0..255 at 0, Bh rows at 256*BK, Bl at 384*BK
    __shared__ __align__(16) short lds[2 * SLABSH];   // 64 KB

    // bijective XCD-aware swizzle (1056 = 8*132)
    int orig = blockIdx.x;
    int wgid = (orig & 7) * (NWG2 / 8) + (orig >> 3);

    // triangular decode: 256-row block p, 128-col block q, q >= 2p
    int rem = wgid, p = 0;
    while (rem >= NQ - 2 * p) { rem -= NQ - 2 * p; ++p; }
    int q = 2 * p + rem;
    int row0 = p * 256, col0 = q * 128;

    int tid = threadIdx.x, lane = tid & 63, wave = tid >> 6;
    int wr = wave >> 1, wc = wave & 1;          // 4M x 2N; per-wave 64x64 out
    int l15 = lane & 15, l4 = lane >> 4;

    // staging: 32 chunks of 16 rows x 32 cols (1 KB); wave w takes u = w + 8j
    const short* gp[4];
    int lof[4];
#pragma unroll
    for (int j = 0; j < 4; ++j) {
        int u = wave + 8 * j;               // 0..31
        const short* src; int base0, r16, sbase;
        if (u < 16)      { src = Xhi; base0 = row0; r16 = u * 16;        sbase = 0; }
        else if (u < 24) { src = Xhi; base0 = col0; r16 = (u - 16) * 16; sbase = 256 * BK; }
        else             { src = Xlo; base0 = col0; r16 = (u - 24) * 16; sbase = 384 * BK; }
        int lrow = lane >> 2;                               // 0..15 row within chunk
        int cu   = (lane & 3) ^ (lrow & 3);                 // pre-swizzled source col unit
        gp[j] = src + (size_t)(base0 + r16 + lrow) * DIMS + cu * 8;
        lof[j] = sbase + r16 * BK;
    }

    f32x4 acc[4][4] = {};

    // prologue: stage K-tile 0 into slab 0
#pragma unroll
    for (int j = 0; j < 4; ++j) gl_lds16(gp[j], lds + lof[j]);
    __syncthreads();

    int cur = 0;
#pragma unroll 1
    for (int t = 0; t < NT; ++t) {
        // issue next-tile stage FIRST (latency hides under ds_read + MFMA)
        if (t + 1 < NT) {
            short* ns = lds + (cur ^ 1) * SLABSH;
#pragma unroll
            for (int j = 0; j < 4; ++j)
                gl_lds16(gp[j] + (size_t)(t + 1) * BK, ns + lof[j]);
        }

        short* S = lds + cur * SLABSH;
        bf16x8 bh[4], bl[4];
#pragma unroll
        for (int n = 0; n < 4; ++n) {
            int rb = wc * 64 + n * 16 + l15;
            int cb = (l4 ^ (rb & 3)) * 8;                  // swizzled read col
            bh[n] = *(const bf16x8*)(S + (256 + rb) * BK + cb);
            bl[n] = *(const bf16x8*)(S + (384 + rb) * BK + cb);
        }
        __builtin_amdgcn_s_setprio(1);
#pragma unroll
        for (int m = 0; m < 4; ++m) {
            int ra = wr * 64 + m * 16 + l15;
            int ca = (l4 ^ (ra & 3)) * 8;
            bf16x8 ah = *(const bf16x8*)(S + ra * BK + ca);
#pragma unroll
            for (int n = 0; n < 4; ++n) {
                acc[m][n] = __builtin_amdgcn_mfma_f32_16x16x32_bf16(ah, bh[n], acc[m][n], 0, 0, 0);
                acc[m][n] = __builtin_amdgcn_mfma_f32_16x16x32_bf16(ah, bl[n], acc[m][n], 0, 0, 0);
            }
        }
        __builtin_amdgcn_s_setprio(0);
        __syncthreads();    // single drain+barrier per K-step (vmcnt+lgkmcnt implicit)
        cur ^= 1;
    }

    // ---- epilogue: per-cell predicate gc > grow; both endpoints updated once ----
    int tcol[4]; float mcol[4], pcol[4];
#pragma unroll
    for (int n = 0; n < 4; ++n) {
        int gc = col0 + wc * 64 + n * 16 + l15;
        tcol[n] = tgt[gc];
        mcol[n] = margin[gc];
        pcol[n] = minpos[gc];
    }
    ull  cmx[4] = {0, 0, 0, 0};
    float cns[4] = {0, 0, 0, 0};
    int  cct[4] = {0, 0, 0, 0};

#pragma unroll
    for (int m = 0; m < 4; ++m) {
#pragma unroll
        for (int r = 0; r < 4; ++r) {
            int grow = row0 + wr * 64 + m * 16 + l4 * 4 + r;
            int trow = tgt[grow];
            float mg = margin[grow], mp = minpos[grow];
            ull rmx = 0; float rns = 0.f; int rct = 0;
#pragma unroll
            for (int n = 0; n < 4; ++n) {
                float s = acc[m][n][r];
                int gc = col0 + wc * 64 + n * 16 + l15;
                if (trow != tcol[n] && gc > grow) {
                    float e = __expf(10.f * s - 5.f);
                    ull pk = (((ull)enc_f(s)) << 32) | (unsigned)gc;
                    rmx = rmx > pk ? rmx : pk;
                    if (s + mg - mp > 0.f) { rct++; rns += e; }
                    ull pk2 = (((ull)enc_f(s)) << 32) | (unsigned)grow;
                    cmx[n] = cmx[n] > pk2 ? cmx[n] : pk2;
                    if (s + mcol[n] - pcol[n] > 0.f) { cct[n]++; cns[n] += e; }
                }
            }
#pragma unroll
            for (int off = 1; off < 16; off <<= 1) {
                ull o = __shfl_xor(rmx, off); rmx = rmx > o ? rmx : o;
                rns += __shfl_xor(rns, off);
                rct += __shfl_xor(rct, off);
            }
            if (l15 == 0 && rmx != 0) {
                atomicMax(&maxneg[grow], rmx);
                if (rct) { atomicAdd(&an_cnt[grow], rct); atomicAdd(&neg_sum[grow], rns); }
            }
        }
    }
#pragma unroll
    for (int n = 0; n < 4; ++n) {
#pragma unroll
        for (int off = 16; off < 64; off <<= 1) {
            ull o = __shfl_xor(cmx[n], off); cmx[n] = cmx[n] > o ? cmx[n] : o;
            cns[n] += __shfl_xor(cns[n], off);
            cct[n] += __shfl_xor(cct[n], off);
        }
        if (lane < 16 && cmx[n] != 0) {
            int gc = col0 + wc * 64 + n * 16 + l15;
            atomicMax(&maxneg[gc], cmx[n]);
            if (cct[n]) { atomicAdd(&an_cnt[gc], cct[n]); atomicAdd(&neg_sum[gc], cns[n]); }
        }
    }
}

// ---------- positive path + argmax repair + outputs + scalar reduction ----------
__global__ __launch_bounds__(256) void finalize_k(const float* __restrict__ X,
                                                  const int* __restrict__ members,
                                                  const int* __restrict__ offs,
                                                  const int* __restrict__ cnt,
                                                  const int* __restrict__ pairoff,
                                                  const float* __restrict__ simbuf,
                                                  const float* __restrict__ sumsq,
                                                  const float* __restrict__ margin,
                                                  const ull* __restrict__ maxneg,
                                                  const int* __restrict__ an_cnt,
                                                  const float* __restrict__ neg_sum,
                                                  float* __restrict__ out) {
    __shared__ int sap[256];
    __shared__ float sps[256];
    __shared__ float smn[256], smg[256];
    __shared__ float sred[8];
    int c = blockIdx.x, tid = threadIdx.x;
    int wave = tid >> 6, lane = tid & 63;
    int k = cnt[c], off = offs[c], spo = pairoff[c];
    int kk = k < 256 ? k : 256;
    sap[tid] = 0; sps[tid] = 0.f;

    for (int a = wave; a < kk; a += 4) {
        int i = members[off + a];
        ull pm = maxneg[i];
        float mn = -1e9f;
        if ((unsigned)(pm >> 32) != enc_f(-1e9f)) {
            int col = (int)(pm & 0xFFFFFFFFu);
            const float4* xi = (const float4*)(X + (size_t)i * DIMS);
            const float4* xj = (const float4*)(X + (size_t)col * DIMS);
            float a0 = 0.f, a1 = 0.f, a2 = 0.f, a3 = 0.f;
#pragma unroll
            for (int t = 0; t < 4; ++t) {
                float4 u = xi[lane + 64 * t], v = xj[lane + 64 * t];
                a0 += u.x * v.x; a1 += u.y * v.y;
                a2 += u.z * v.z; a3 += u.w * v.w;
            }
            float s = (a0 + a1) + (a2 + a3);
#pragma unroll
            for (int o = 1; o < 64; o <<= 1) s += __shfl_xor(s, o);
            mn = s;
        }
        if (lane == 0) { smn[a] = mn; smg[a] = margin[i]; }
    }
    __syncthreads();

    for (int p = tid; p < kk * kk; p += 256) {
        int a = p / kk;
        float s;
        if (spo >= 0) {
            s = simbuf[spo + p];
        } else {
            int b = p - a * kk;
            int i = members[off + a], j = members[off + b];
            s = (i == j) ? sumsq[i]
                         : dot1024(X + (size_t)i * DIMS, X + (size_t)j * DIMS);
        }
        if (s < 1.0f && (smn[a] - s + smg[a] > 0.f)) {
            atomicAdd(&sap[a], 1);
            atomicAdd(&sps[a], __expf(-2.f * s + 1.f));
        }
    }
    __syncthreads();

    float bl = 0.f, bt = 0.f;
    for (int a = tid; a < kk; a += 256) {
        int i = members[off + a];
        int ap = sap[a];
        int an = an_cnt[i];
        bool valid = (ap > 0) && (an > 0);
        float pl = log1pf(sps[a]);
        float nl = 0.2f * log1pf(neg_sum[i]);
        out[1 + i]              = valid ? 1.f : 0.f;
        out[1 + N_ROWS + i]     = valid ? (float)ap : 0.f;
        out[1 + 2 * N_ROWS + i] = valid ? (float)an : 0.f;
        bl += valid ? (pl + nl) : 0.f;
        bt += valid ? (float)(ap + an) : 0.f;
    }
#pragma unroll
    for (int o = 1; o < 64; o <<= 1) {
        bl += __shfl_xor(bl, o);
        bt += __shfl_xor(bt, o);
    }
    if (lane == 0) { sred[wave] = bl; sred[4 + wave] = bt; }
    __syncthreads();
    if (tid == 0) {
        float L = sred[0] + sred[1] + sred[2] + sred[3];
        float T = sred[4] + sred[5] + sred[6] + sred[7];
        atomicAdd(&out[0], L / (float)N_ROWS);
        atomicAdd(&out[1 + 3 * N_ROWS], T);
    }
}

// ---------- host ----------
extern "C" void kernel_launch(void* const* d_in, const int* in_sizes, int n_in,
                              void* d_out, int out_size, void* d_ws, size_t ws_size,
                              hipStream_t stream) {
    const float* X      = (const float*)d_in[0];
    const int*   rawTgt = (const int*)d_in[1];
    const float* margin = (const float*)d_in[2];
    float* out = (float*)d_out;

    char* ws = (char*)d_ws;
    short* Xhi = (short*)ws;                                   // 16 MB
    short* Xlo = (short*)(ws + (size_t)16 * 1024 * 1024);      // 16 MB
    char* p = ws + (size_t)32 * 1024 * 1024;
    float* sumsq    = (float*)p;  p += (size_t)N_ROWS * 4;
    float* minpos   = (float*)p;  p += (size_t)N_ROWS * 4;
    ull*   maxneg   = (ull*)p;    p += (size_t)N_ROWS * 8;
    int*   an_cnt   = (int*)p;    p += (size_t)N_ROWS * 4;
    float* neg_sum  = (float*)p;  p += (size_t)N_ROWS * 4;
    int*   tgt      = (int*)p;    p += (size_t)N_ROWS * 4;
    int*   members  = (int*)p;    p += (size_t)N_ROWS * 4;
    int*   cnt      = (int*)p;    p += (size_t)NCLS * 4;
    int*   offs     = (int*)p;    p += (size_t)NCLS * 4;
    int*   pairoff  = (int*)p;    p += (size_t)NCLS * 4;
    float* simbuf   = (float*)p;  // up to 4 MB if workspace allows

    size_t used = (size_t)(p - ws);
    int simcap = (ws_size >= used + (size_t)4 * 1024 * 1024) ? (1 << 20) : 0;

    setup_k<<<1 + N_ROWS / 4, 256, 0, stream>>>(X, rawTgt, Xhi, Xlo, sumsq, tgt, cnt, offs,
                                                pairoff, members, an_cnt, neg_sum, maxneg,
                                                out, simcap);
    minpos_k<<<NCLS, 512, 0, stream>>>(X, members, offs, cnt, pairoff, sumsq, minpos, simbuf);
    fused_k<<<NWG2, 512, 0, stream>>>(Xhi, Xlo, tgt, margin, minpos, maxneg, an_cnt, neg_sum);
    finalize_k<<<NCLS, 256, 0, stream>>>(X, members, offs, cnt, pairoff, simbuf, sumsq,
                                         margin, maxneg, an_cnt, neg_sum, out);
}

// Round 19
// 281.217 us; speedup vs baseline: 1.2751x; 1.0555x over previous
//
#include <hip/hip_runtime.h>
#include <math.h>

#define N_ROWS 8192
#define DIMS   1024
#define NCLS   512
#define BK     32
#define NT     (DIMS / BK)           // 32 K-tiles
#define NQ     64                    // 8192/128 col-blocks
#define NWG2   1056                  // triangular 256x128 tiles (= 8*132)
#define SLABSH (512 * BK)            // shorts per slab: Ah256 + Bh128 + Bl128 rows
#define CA     16                    // class rows staged per LDS chunk (64 KB)

typedef __attribute__((ext_vector_type(8))) short bf16x8;
typedef __attribute__((ext_vector_type(4))) float f32x4;
typedef unsigned long long ull;

// ---------- helpers ----------
__device__ __forceinline__ unsigned short f2bf(float f) {
    unsigned u = __float_as_uint(f);
    u += 0x7FFFu + ((u >> 16) & 1u);   // RNE
    return (unsigned short)(u >> 16);
}
__device__ __forceinline__ float bf2f(unsigned short h) {
    return __uint_as_float(((unsigned)h) << 16);
}
// monotone float<->uint for atomic min/max
__device__ __forceinline__ unsigned enc_f(float x) {
    unsigned u = __float_as_uint(x);
    return (u & 0x80000000u) ? ~u : (u | 0x80000000u);
}
__device__ __forceinline__ float dec_f(unsigned u) {
    return (u & 0x80000000u) ? __uint_as_float(u ^ 0x80000000u) : __uint_as_float(~u);
}

__device__ __forceinline__ float dot1024(const float* __restrict__ xi,
                                         const float* __restrict__ xj) {
    const float4* u4 = (const float4*)xi;
    const float4* v4 = (const float4*)xj;
    float a0 = 0.f, a1 = 0.f, a2 = 0.f, a3 = 0.f;
#pragma unroll 8
    for (int q = 0; q < DIMS / 4; ++q) {
        float4 u = u4[q], v = v4[q];
        a0 += u.x * v.x; a1 += u.y * v.y;
        a2 += u.z * v.z; a3 += u.w * v.w;
    }
    return (a0 + a1) + (a2 + a3);
}

typedef __attribute__((address_space(1))) const void* as1_cvp;
typedef __attribute__((address_space(3))) void* as3_vp;
__device__ __forceinline__ void gl_lds16(const void* g, void* l) {
    __builtin_amdgcn_global_load_lds((as1_cvp)g, (as3_vp)l, 16, 0, 0);
}

// ---------- fused setup: block 0 = bucketing, blocks 1..2048 = prep + init ----------
__global__ __launch_bounds__(256) void setup_k(const float* __restrict__ X,
                                               const int* __restrict__ raw,
                                               short* __restrict__ Xhi,
                                               short* __restrict__ Xlo,
                                               float* __restrict__ sumsq,
                                               int* __restrict__ tgt,
                                               int* __restrict__ cnt,
                                               int* __restrict__ offs,
                                               int* __restrict__ pairoff,
                                               int* __restrict__ members,
                                               int* __restrict__ an_cnt,
                                               float* __restrict__ neg_sum,
                                               ull* __restrict__ maxneg,
                                               float* __restrict__ out,
                                               int simcap) {
    __shared__ int sflag;
    __shared__ int scnt[NCLS], soff[NCLS], spair[NCLS], scur[NCLS];
    __shared__ int schunk[16], schunkp[16];
    int tid = threadIdx.x;

    if (blockIdx.x == 0) {
        if (tid == 0) { sflag = 0; out[0] = 0.f; out[1 + 3 * N_ROWS] = 0.f; }
        for (int c = tid; c < NCLS; c += 256) scnt[c] = 0;
        __syncthreads();
        int any = 0;
        for (int i = tid; i < N_ROWS / 2; i += 256) any |= raw[2 * i + 1];
        if (any) atomicOr(&sflag, 1);
        __syncthreads();
        int is32 = sflag;     // nonzero odd 32-bit words => targets are int32
        for (int i = tid; i < N_ROWS; i += 256) {
            int t = is32 ? raw[i] : raw[2 * i];
            tgt[i] = t;
            if ((unsigned)t < NCLS) atomicAdd(&scnt[t], 1);
        }
        __syncthreads();
        if (tid < 16) {
            int s = 0, sp = 0;
            for (int c = tid * 32; c < tid * 32 + 32; ++c) {
                int k = scnt[c]; int kk = k < 256 ? k : 256;
                s += k; sp += kk * kk;
            }
            schunk[tid] = s; schunkp[tid] = sp;
        }
        __syncthreads();
        if (tid == 0) {
            int s = 0, sp = 0;
            for (int t = 0; t < 16; ++t) {
                int a = schunk[t], b = schunkp[t];
                schunk[t] = s; schunkp[t] = sp;
                s += a; sp += b;
            }
        }
        __syncthreads();
        if (tid < 16) {
            int s = schunk[tid], sp = schunkp[tid];
            for (int c = tid * 32; c < tid * 32 + 32; ++c) {
                int k = scnt[c]; int kk = k < 256 ? k : 256;
                soff[c] = s; scur[c] = s;
                spair[c] = (simcap > 0 && sp + kk * kk <= simcap) ? sp : -1;
                s += k; sp += kk * kk;
            }
        }
        __syncthreads();
        for (int i = tid; i < N_ROWS; i += 256) {
            int t = tgt[i];
            if ((unsigned)t < NCLS) {
                int p = atomicAdd(&scur[t], 1);
                members[p] = i;
            }
        }
        for (int c = tid; c < NCLS; c += 256) {
            cnt[c] = scnt[c]; offs[c] = soff[c]; pairoff[c] = spair[c];
        }
    } else {
        int rowbase = (blockIdx.x - 1) * 4;
        int row  = rowbase + (tid >> 6);
        int lane = tid & 63;
        const float4* xr = (const float4*)(X + (size_t)row * DIMS);
        short4* oh = (short4*)(Xhi + (size_t)row * DIMS);
        short4* ol = (short4*)(Xlo + (size_t)row * DIMS);
        float ss = 0.f;
#pragma unroll
        for (int t = 0; t < 4; ++t) {
            float4 v = xr[lane + 64 * t];
            ss += v.x * v.x + v.y * v.y + v.z * v.z + v.w * v.w;
            short4 h, l;
            unsigned short hx = f2bf(v.x); h.x = (short)hx; l.x = (short)f2bf(v.x - bf2f(hx));
            unsigned short hy = f2bf(v.y); h.y = (short)hy; l.y = (short)f2bf(v.y - bf2f(hy));
            unsigned short hz = f2bf(v.z); h.z = (short)hz; l.z = (short)f2bf(v.z - bf2f(hz));
            unsigned short hw = f2bf(v.w); h.w = (short)hw; l.w = (short)f2bf(v.w - bf2f(hw));
            oh[lane + 64 * t] = h;
            ol[lane + 64 * t] = l;
        }
#pragma unroll
        for (int off = 1; off < 64; off <<= 1) ss += __shfl_xor(ss, off);
        if (lane == 0) sumsq[row] = ss;
        if (tid < 4) {
            int r = rowbase + tid;
            an_cnt[r] = 0; neg_sum[r] = 0.f;
            maxneg[r] = ((ull)enc_f(-1e9f)) << 32;
        }
    }
}

// ---------- min_pos: LDS-staged class grams, 8 waves, 4 chains (2a x 2b) ----------
__global__ __launch_bounds__(512) void minpos_k(const float* __restrict__ X,
                                                const int* __restrict__ members,
                                                const int* __restrict__ offs,
                                                const int* __restrict__ cnt,
                                                const int* __restrict__ pairoff,
                                                const float* __restrict__ sumsq,
                                                float* __restrict__ minpos,
                                                float* __restrict__ simbuf) {
    __shared__ __align__(16) float srows[CA][DIMS];   // 64 KB
    __shared__ unsigned smin[256];
    int c = blockIdx.x, tid = threadIdx.x;
    int wave = tid >> 6, lane = tid & 63;             // 8 waves
    int k = cnt[c], off = offs[c], spo = pairoff[c];
    for (int t = tid; t < 256; t += 512) smin[t] = enc_f(1e9f);
    int kk = k < 256 ? k : 256;
    __syncthreads();
    for (int a0 = 0; a0 < kk; a0 += CA) {
        int na = (kk - a0 < CA) ? (kk - a0) : CA;
        for (int idx = tid; idx < na * 256; idx += 512) {
            int r = idx >> 8, c4 = idx & 255;
            int i = members[off + a0 + r];
            ((float4*)&srows[r][0])[c4] = ((const float4*)(X + (size_t)i * DIMS))[c4];
        }
        __syncthreads();
        // 2 b-rows in registers x 2 a-rows from LDS = 4 independent chains
        for (int b = wave; b < kk; b += 16) {
            int bB = b + 8;
            bool hasB = bB < kk;
            int j0 = members[off + b];
            int j1 = members[off + (hasB ? bB : b)];
            const float4* xj0 = (const float4*)(X + (size_t)j0 * DIMS);
            const float4* xj1 = (const float4*)(X + (size_t)j1 * DIMS);
            float4 rj0[4], rj1[4];
#pragma unroll
            for (int t = 0; t < 4; ++t) { rj0[t] = xj0[lane + 64 * t]; rj1[t] = xj1[lane + 64 * t]; }
            int a = 0;
            for (; a + 2 <= na; a += 2) {
                int i0 = members[off + a0 + a];
                int i1 = members[off + a0 + a + 1];
                float p00 = 0.f, p01 = 0.f, p10 = 0.f, p11 = 0.f;
#pragma unroll
                for (int t = 0; t < 4; ++t) {
                    float4 u0 = ((const float4*)&srows[a][0])[lane + 64 * t];
                    float4 u1 = ((const float4*)&srows[a + 1][0])[lane + 64 * t];
                    p00 += u0.x * rj0[t].x + u0.y * rj0[t].y + u0.z * rj0[t].z + u0.w * rj0[t].w;
                    p01 += u0.x * rj1[t].x + u0.y * rj1[t].y + u0.z * rj1[t].z + u0.w * rj1[t].w;
                    p10 += u1.x * rj0[t].x + u1.y * rj0[t].y + u1.z * rj0[t].z + u1.w * rj0[t].w;
                    p11 += u1.x * rj1[t].x + u1.y * rj1[t].y + u1.z * rj1[t].z + u1.w * rj1[t].w;
                }
#pragma unroll
                for (int o = 1; o < 64; o <<= 1) {
                    p00 += __shfl_xor(p00, o);
                    p01 += __shfl_xor(p01, o);
                    p10 += __shfl_xor(p10, o);
                    p11 += __shfl_xor(p11, o);
                }
                if (i0 == j0) p00 = sumsq[i0];
                if (i1 == j0) p10 = sumsq[i1];
                if (i0 == j1) p01 = sumsq[i0];
                if (i1 == j1) p11 = sumsq[i1];
                if (lane == 0) {
                    if (spo >= 0) {
                        simbuf[spo + (a0 + a) * kk + b] = p00;
                        simbuf[spo + (a0 + a + 1) * kk + b] = p10;
                        if (hasB) {
                            simbuf[spo + (a0 + a) * kk + bB] = p01;
                            simbuf[spo + (a0 + a + 1) * kk + bB] = p11;
                        }
                    }
                    if (p00 < 1.0f) atomicMin(&smin[a0 + a], enc_f(p00));
                    if (p10 < 1.0f) atomicMin(&smin[a0 + a + 1], enc_f(p10));
                    if (hasB) {
                        if (p01 < 1.0f) atomicMin(&smin[a0 + a], enc_f(p01));
                        if (p11 < 1.0f) atomicMin(&smin[a0 + a + 1], enc_f(p11));
                    }
                }
            }
            if (a < na) {
                int i0 = members[off + a0 + a];
                float p00 = 0.f, p01 = 0.f;
#pragma unroll
                for (int t = 0; t < 4; ++t) {
                    float4 u0 = ((const float4*)&srows[a][0])[lane + 64 * t];
                    p00 += u0.x * rj0[t].x + u0.y * rj0[t].y + u0.z * rj0[t].z + u0.w * rj0[t].w;
                    p01 += u0.x * rj1[t].x + u0.y * rj1[t].y + u0.z * rj1[t].z + u0.w * rj1[t].w;
                }
#pragma unroll
                for (int o = 1; o < 64; o <<= 1) {
                    p00 += __shfl_xor(p00, o);
                    p01 += __shfl_xor(p01, o);
                }
                if (i0 == j0) p00 = sumsq[i0];
                if (i0 == j1) p01 = sumsq[i0];
                if (lane == 0) {
                    if (spo >= 0) {
                        simbuf[spo + (a0 + a) * kk + b] = p00;
                        if (hasB) simbuf[spo + (a0 + a) * kk + bB] = p01;
                    }
                    if (p00 < 1.0f) atomicMin(&smin[a0 + a], enc_f(p00));
                    if (hasB && p01 < 1.0f) atomicMin(&smin[a0 + a], enc_f(p01));
                }
            }
        }
        __syncthreads();
    }
    for (int a = tid; a < kk; a += 512) minpos[members[off + a]] = dec_f(smin[a]);
}

// ---------- main fused GEMM: 256x128, BK=32, stage-first dbuf (r16/r18 form) ----------
__global__ __launch_bounds__(512, 4) void fused_k(const short* __restrict__ Xhi,
                                                  const short* __restrict__ Xlo,
                                                  const int* __restrict__ tgt,
                                                  const float* __restrict__ margin,
                                                  const float* __restrict__ minpos,
                                                  ull* __restrict__ maxneg,
                                                  int* __restrict__ an_cnt,
                                                  float* __restrict__ neg_sum) {
    // slab layout (shorts): Ah rows 0..255 at 0, Bh rows at 256*BK, Bl at 384*BK
    __shared__ __align__(16) short lds[2 * SLABSH];   // 64 KB

    // bijective XCD-aware swizzle (1056 = 8*132)
    int orig = blockIdx.x;
    int wgid = (orig & 7) * (NWG2 / 8) + (orig >> 3);

    // triangular decode: 256-row block p, 128-col block q, q >= 2p
    int rem = wgid, p = 0;
    while (rem >= NQ - 2 * p) { rem -= NQ - 2 * p; ++p; }
    int q = 2 * p + rem;
    int row0 = p * 256, col0 = q * 128;

    int tid = threadIdx.x, lane = tid & 63, wave = tid >> 6;
    int wr = wave >> 1, wc = wave & 1;          // 4M x 2N; per-wave 64x64 out
    int l15 = lane & 15, l4 = lane >> 4;

    // staging: 32 chunks of 16 rows x 32 cols (1 KB); wave w takes u = w + 8j
    const short* gp[4];
    int lof[4];
#pragma unroll
    for (int j = 0; j < 4; ++j) {
        int u = wave + 8 * j;               // 0..31
        const short* src; int base0, r16, sbase;
        if (u < 16)      { src = Xhi; base0 = row0; r16 = u * 16;        sbase = 0; }
        else if (u < 24) { src = Xhi; base0 = col0; r16 = (u - 16) * 16; sbase = 256 * BK; }
        else             { src = Xlo; base0 = col0; r16 = (u - 24) * 16; sbase = 384 * BK; }
        int lrow = lane >> 2;                               // 0..15 row within chunk
        int cu   = (lane & 3) ^ (lrow & 3);                 // pre-swizzled source col unit
        gp[j] = src + (size_t)(base0 + r16 + lrow) * DIMS + cu * 8;
        lof[j] = sbase + r16 * BK;
    }

    f32x4 acc[4][4] = {};

    // prologue: stage K-tile 0 into slab 0
#pragma unroll
    for (int j = 0; j < 4; ++j) gl_lds16(gp[j], lds + lof[j]);
    __syncthreads();

    int cur = 0;
#pragma unroll 1
    for (int t = 0; t < NT; ++t) {
        // issue next-tile stage FIRST (latency hides under ds_read + MFMA)
        if (t + 1 < NT) {
            short* ns = lds + (cur ^ 1) * SLABSH;
#pragma unroll
            for (int j = 0; j < 4; ++j)
                gl_lds16(gp[j] + (size_t)(t + 1) * BK, ns + lof[j]);
        }

        short* S = lds + cur * SLABSH;
        bf16x8 bh[4], bl[4];
#pragma unroll
        for (int n = 0; n < 4; ++n) {
            int rb = wc * 64 + n * 16 + l15;
            int cb = (l4 ^ (rb & 3)) * 8;                  // swizzled read col
            bh[n] = *(const bf16x8*)(S + (256 + rb) * BK + cb);
            bl[n] = *(const bf16x8*)(S + (384 + rb) * BK + cb);
        }
        __builtin_amdgcn_s_setprio(1);
#pragma unroll
        for (int m = 0; m < 4; ++m) {
            int ra = wr * 64 + m * 16 + l15;
            int ca = (l4 ^ (ra & 3)) * 8;
            bf16x8 ah = *(const bf16x8*)(S + ra * BK + ca);
#pragma unroll
            for (int n = 0; n < 4; ++n) {
                acc[m][n] = __builtin_amdgcn_mfma_f32_16x16x32_bf16(ah, bh[n], acc[m][n], 0, 0, 0);
                acc[m][n] = __builtin_amdgcn_mfma_f32_16x16x32_bf16(ah, bl[n], acc[m][n], 0, 0, 0);
            }
        }
        __builtin_amdgcn_s_setprio(0);
        __syncthreads();    // single drain+barrier per K-step (vmcnt+lgkmcnt implicit)
        cur ^= 1;
    }

    // ---- epilogue: per-cell predicate gc > grow; both endpoints updated once ----
    int tcol[4]; float mcol[4], pcol[4];
#pragma unroll
    for (int n = 0; n < 4; ++n) {
        int gc = col0 + wc * 64 + n * 16 + l15;
        tcol[n] = tgt[gc];
        mcol[n] = margin[gc];
        pcol[n] = minpos[gc];
    }
    ull  cmx[4] = {0, 0, 0, 0};
    float cns[4] = {0, 0, 0, 0};
    int  cct[4] = {0, 0, 0, 0};

#pragma unroll
    for (int m = 0; m < 4; ++m) {
#pragma unroll
        for (int r = 0; r < 4; ++r) {
            int grow = row0 + wr * 64 + m * 16 + l4 * 4 + r;
            int trow = tgt[grow];
            float mg = margin[grow], mp = minpos[grow];
            ull rmx = 0; float rns = 0.f; int rct = 0;
#pragma unroll
            for (int n = 0; n < 4; ++n) {
                float s = acc[m][n][r];
                int gc = col0 + wc * 64 + n * 16 + l15;
                if (trow != tcol[n] && gc > grow) {
                    float e = __expf(10.f * s - 5.f);
                    ull pk = (((ull)enc_f(s)) << 32) | (unsigned)gc;
                    rmx = rmx > pk ? rmx : pk;
                    if (s + mg - mp > 0.f) { rct++; rns += e; }
                    ull pk2 = (((ull)enc_f(s)) << 32) | (unsigned)grow;
                    cmx[n] = cmx[n] > pk2 ? cmx[n] : pk2;
                    if (s + mcol[n] - pcol[n] > 0.f) { cct[n]++; cns[n] += e; }
                }
            }
#pragma unroll
            for (int off = 1; off < 16; off <<= 1) {
                ull o = __shfl_xor(rmx, off); rmx = rmx > o ? rmx : o;
                rns += __shfl_xor(rns, off);
                rct += __shfl_xor(rct, off);
            }
            if (l15 == 0 && rmx != 0) {
                atomicMax(&maxneg[grow], rmx);
                if (rct) { atomicAdd(&an_cnt[grow], rct); atomicAdd(&neg_sum[grow], rns); }
            }
        }
    }
#pragma unroll
    for (int n = 0; n < 4; ++n) {
#pragma unroll
        for (int off = 16; off < 64; off <<= 1) {
            ull o = __shfl_xor(cmx[n], off); cmx[n] = cmx[n] > o ? cmx[n] : o;
            cns[n] += __shfl_xor(cns[n], off);
            cct[n] += __shfl_xor(cct[n], off);
        }
        if (lane < 16 && cmx[n] != 0) {
            int gc = col0 + wc * 64 + n * 16 + l15;
            atomicMax(&maxneg[gc], cmx[n]);
            if (cct[n]) { atomicAdd(&an_cnt[gc], cct[n]); atomicAdd(&neg_sum[gc], cns[n]); }
        }
    }
}

// ---------- positive path + argmax repair + outputs + scalar reduction ----------
__global__ __launch_bounds__(256) void finalize_k(const float* __restrict__ X,
                                                  const int* __restrict__ members,
                                                  const int* __restrict__ offs,
                                                  const int* __restrict__ cnt,
                                                  const int* __restrict__ pairoff,
                                                  const float* __restrict__ simbuf,
                                                  const float* __restrict__ sumsq,
                                                  const float* __restrict__ margin,
                                                  const ull* __restrict__ maxneg,
                                                  const int* __restrict__ an_cnt,
                                                  const float* __restrict__ neg_sum,
                                                  float* __restrict__ out) {
    __shared__ int sap[256];
    __shared__ float sps[256];
    __shared__ float smn[256], smg[256];
    __shared__ float sred[8];
    int c = blockIdx.x, tid = threadIdx.x;
    int wave = tid >> 6, lane = tid & 63;
    int k = cnt[c], off = offs[c], spo = pairoff[c];
    int kk = k < 256 ? k : 256;
    sap[tid] = 0; sps[tid] = 0.f;

    for (int a = wave; a < kk; a += 4) {
        int i = members[off + a];
        ull pm = maxneg[i];
        float mn = -1e9f;
        if ((unsigned)(pm >> 32) != enc_f(-1e9f)) {
            int col = (int)(pm & 0xFFFFFFFFu);
            const float4* xi = (const float4*)(X + (size_t)i * DIMS);
            const float4* xj = (const float4*)(X + (size_t)col * DIMS);
            float a0 = 0.f, a1 = 0.f, a2 = 0.f, a3 = 0.f;
#pragma unroll
            for (int t = 0; t < 4; ++t) {
                float4 u = xi[lane + 64 * t], v = xj[lane + 64 * t];
                a0 += u.x * v.x; a1 += u.y * v.y;
                a2 += u.z * v.z; a3 += u.w * v.w;
            }
            float s = (a0 + a1) + (a2 + a3);
#pragma unroll
            for (int o = 1; o < 64; o <<= 1) s += __shfl_xor(s, o);
            mn = s;
        }
        if (lane == 0) { smn[a] = mn; smg[a] = margin[i]; }
    }
    __syncthreads();

    for (int p = tid; p < kk * kk; p += 256) {
        int a = p / kk;
        float s;
        if (spo >= 0) {
            s = simbuf[spo + p];
        } else {
            int b = p - a * kk;
            int i = members[off + a], j = members[off + b];
            s = (i == j) ? sumsq[i]
                         : dot1024(X + (size_t)i * DIMS, X + (size_t)j * DIMS);
        }
        if (s < 1.0f && (smn[a] - s + smg[a] > 0.f)) {
            atomicAdd(&sap[a], 1);
            atomicAdd(&sps[a], __expf(-2.f * s + 1.f));
        }
    }
    __syncthreads();

    float bl = 0.f, bt = 0.f;
    for (int a = tid; a < kk; a += 256) {
        int i = members[off + a];
        int ap = sap[a];
        int an = an_cnt[i];
        bool valid = (ap > 0) && (an > 0);
        float pl = log1pf(sps[a]);
        float nl = 0.2f * log1pf(neg_sum[i]);
        out[1 + i]              = valid ? 1.f : 0.f;
        out[1 + N_ROWS + i]     = valid ? (float)ap : 0.f;
        out[1 + 2 * N_ROWS + i] = valid ? (float)an : 0.f;
        bl += valid ? (pl + nl) : 0.f;
        bt += valid ? (float)(ap + an) : 0.f;
    }
#pragma unroll
    for (int o = 1; o < 64; o <<= 1) {
        bl += __shfl_xor(bl, o);
        bt += __shfl_xor(bt, o);
    }
    if (lane == 0) { sred[wave] = bl; sred[4 + wave] = bt; }
    __syncthreads();
    if (tid == 0) {
        float L = sred[0] + sred[1] + sred[2] + sred[3];
        float T = sred[4] + sred[5] + sred[6] + sred[7];
        atomicAdd(&out[0], L / (float)N_ROWS);
        atomicAdd(&out[1 + 3 * N_ROWS], T);
    }
}

// ---------- host ----------
extern "C" void kernel_launch(void* const* d_in, const int* in_sizes, int n_in,
                              void* d_out, int out_size, void* d_ws, size_t ws_size,
                              hipStream_t stream) {
    const float* X      = (const float*)d_in[0];
    const int*   rawTgt = (const int*)d_in[1];
    const float* margin = (const float*)d_in[2];
    float* out = (float*)d_out;

    char* ws = (char*)d_ws;
    short* Xhi = (short*)ws;                                   // 16 MB
    short* Xlo = (short*)(ws + (size_t)16 * 1024 * 1024);      // 16 MB
    char* p = ws + (size_t)32 * 1024 * 1024;
    float* sumsq    = (float*)p;  p += (size_t)N_ROWS * 4;
    float* minpos   = (float*)p;  p += (size_t)N_ROWS * 4;
    ull*   maxneg   = (ull*)p;    p += (size_t)N_ROWS * 8;
    int*   an_cnt   = (int*)p;    p += (size_t)N_ROWS * 4;
    float* neg_sum  = (float*)p;  p += (size_t)N_ROWS * 4;
    int*   tgt      = (int*)p;    p += (size_t)N_ROWS * 4;
    int*   members  = (int*)p;    p += (size_t)N_ROWS * 4;
    int*   cnt      = (int*)p;    p += (size_t)NCLS * 4;
    int*   offs     = (int*)p;    p += (size_t)NCLS * 4;
    int*   pairoff  = (int*)p;    p += (size_t)NCLS * 4;
    float* simbuf   = (float*)p;  // up to 4 MB if workspace allows

    size_t used = (size_t)(p - ws);
    int simcap = (ws_size >= used + (size_t)4 * 1024 * 1024) ? (1 << 20) : 0;

    setup_k<<<1 + N_ROWS / 4, 256, 0, stream>>>(X, rawTgt, Xhi, Xlo, sumsq, tgt, cnt, offs,
                                                pairoff, members, an_cnt, neg_sum, maxneg,
                                                out, simcap);
    minpos_k<<<NCLS, 512, 0, stream>>>(X, members, offs, cnt, pairoff, sumsq, minpos, simbuf);
    fused_k<<<NWG2, 512, 0, stream>>>(Xhi, Xlo, tgt, margin, minpos, maxneg, an_cnt, neg_sum);
    finalize_k<<<NCLS, 256, 0, stream>>>(X, members, offs, cnt, pairoff, simbuf, sumsq,
                                         margin, maxneg, an_cnt, neg_sum, out);
}